// Round 5
// baseline (47.942 us; speedup 1.0000x reference)
//
#include <hip/hip_runtime.h>
#include <stdint.h>

#define DIM_IN  4096
#define DIM_OUT 4096
#define BATCH   64
// words along dim_in: 4096/64 = 64

typedef unsigned long long u64;
typedef uint32_t u32;

// ---------------------------------------------------------------------------
// Input-format detection (first 8 u32 words):
//   int32 0/1 or float 0.0/1.0 -> "word" layout (4B per bool)
//   uint8 0/1                  -> "byte" layout (1B per bool)
// Round-3/4 FETCH_SIZE (33.4 MB > byte-ideal 16.7 MB) says these inputs are
// word-encoded; byte path kept for robustness (misclassify P ~ 2^-192).
// ---------------------------------------------------------------------------
__device__ __forceinline__ bool is_word_fmt(const u32* __restrict__ p) {
    bool words = true;
#pragma unroll
    for (int i = 0; i < 8; ++i) {
        u32 v = p[i];
        if (v > 1u && v != 0x3F800000u) words = false;
    }
    return words;
}

// ---------------------------------------------------------------------------
// K1 (fused pack), 528 blocks x 256 threads.
//
// blocks 0..511: STREAMING mask pack. Block b: w = b>>3 (u64 row-group),
//   q = b&7 (8-row slice). The block reads rows w*64+q*8 .. +7 — a CONTIGUOUS
//   128 KB slab (sequential DRAM pages), 16 KB per row via 256 thr x 4 uint4
//   segments. Thread t touches the same 16 columns (o = s*1024+t*4+c) on
//   every row -> bit-slice accumulates in registers, no transpose.
//   Byte q of mp[w][o] (little-endian => bit position q*8+r = row offset) is
//   stored directly; bnn still reads one u64 per (w,o).
//
// blocks 512..527: x pack via wave ballot (64 waves x 64 words).
// ---------------------------------------------------------------------------
__global__ __launch_bounds__(256) void pack_kernel(
        const void* __restrict__ masks, const void* __restrict__ x,
        u64* __restrict__ mp, u64* __restrict__ xp) {
    const int bid = blockIdx.x;
    if (bid < 512) {
        const bool words = is_word_fmt((const u32*)masks);
        const int w = bid >> 3;            // 0..63
        const int q = bid & 7;             // 0..7 (8-row slice)
        const int row0 = w * 64 + q * 8;
        const int t = threadIdx.x;

        u32 acc[4][4] = {};                // [segment][col], values fit in 8 bits

        if (words) {
            const u32* pw = (const u32*)masks + (size_t)row0 * DIM_OUT + t * 4;
#pragma unroll
            for (int r = 0; r < 8; ++r) {
                const size_t ro = (size_t)r * DIM_OUT;
                const uint4 v0 = *reinterpret_cast<const uint4*>(pw + ro);
                const uint4 v1 = *reinterpret_cast<const uint4*>(pw + ro + 1024);
                const uint4 v2 = *reinterpret_cast<const uint4*>(pw + ro + 2048);
                const uint4 v3 = *reinterpret_cast<const uint4*>(pw + ro + 3072);
                acc[0][0] |= (u32)(v0.x != 0u) << r;
                acc[0][1] |= (u32)(v0.y != 0u) << r;
                acc[0][2] |= (u32)(v0.z != 0u) << r;
                acc[0][3] |= (u32)(v0.w != 0u) << r;
                acc[1][0] |= (u32)(v1.x != 0u) << r;
                acc[1][1] |= (u32)(v1.y != 0u) << r;
                acc[1][2] |= (u32)(v1.z != 0u) << r;
                acc[1][3] |= (u32)(v1.w != 0u) << r;
                acc[2][0] |= (u32)(v2.x != 0u) << r;
                acc[2][1] |= (u32)(v2.y != 0u) << r;
                acc[2][2] |= (u32)(v2.z != 0u) << r;
                acc[2][3] |= (u32)(v2.w != 0u) << r;
                acc[3][0] |= (u32)(v3.x != 0u) << r;
                acc[3][1] |= (u32)(v3.y != 0u) << r;
                acc[3][2] |= (u32)(v3.z != 0u) << r;
                acc[3][3] |= (u32)(v3.w != 0u) << r;
            }
        } else {
            // byte layout: row = 4096 B; thread t's 4 columns of segment s are
            // one u32 at byte offset s*1024 + t*4. Byte c != 0 -> bit.
            const u32* pb = (const u32*)((const uint8_t*)masks
                              + (size_t)row0 * DIM_OUT) + t;
#pragma unroll
            for (int r = 0; r < 8; ++r) {
                const size_t ro = (size_t)r * (DIM_OUT / 4);
                u32 b[4];
                b[0] = pb[ro];
                b[1] = pb[ro + 256];
                b[2] = pb[ro + 512];
                b[3] = pb[ro + 768];
#pragma unroll
                for (int s = 0; s < 4; ++s) {
#pragma unroll
                    for (int c = 0; c < 4; ++c)
                        acc[s][c] |= (u32)(((b[s] >> (8 * c)) & 0xFFu) != 0u) << r;
                }
            }
        }

        uint8_t* mpb = (uint8_t*)mp;
#pragma unroll
        for (int s = 0; s < 4; ++s) {
#pragma unroll
            for (int c = 0; c < 4; ++c) {
                const int o = s * 1024 + t * 4 + c;
                mpb[((size_t)w * DIM_OUT + o) * 8 + q] = (uint8_t)acc[s][c];
            }
        }
    } else {
        // ------------------- x pack -------------------
        const bool words = is_word_fmt((const u32*)x);
        const int bxid = bid - 512;                           // 0..15
        const int wave = bxid * 4 + (threadIdx.x >> 6);       // 0..63
        const int lane = threadIdx.x & 63;
        const int base = wave * 64;                           // word index base

#pragma unroll 16
        for (int k = 0; k < 64; ++k) {
            const int idx = base + k;                         // 0..4095
            const size_t e = (size_t)idx * 64 + lane;         // element index
            bool pred;
            if (words) pred = ((const u32*)x)[e] != 0u;
            else       pred = ((const uint8_t*)x)[e] != 0u;
            const u64 m = __ballot(pred);
            if (lane == 0) xp[idx] = m;
        }
    }
}

// ---------------------------------------------------------------------------
// K2: out[b][o] = ((4096 - sum_w popc(xp[b][w] ^ mp[w][o])) > thr[o]) ? 1 : 0
// Output dtype INT32 (bool output -> int32 harness path).
// Grid: (16 o-blocks, 16 b-blocks) x 256 threads; 4 batch rows per thread.
// mp loads coalesced (consecutive o per lane); xp block-uniform -> scalar.
// ---------------------------------------------------------------------------
__global__ __launch_bounds__(256) void bnn_kernel(
        const u64* __restrict__ mp, const u64* __restrict__ xp,
        const int* __restrict__ thr, int* __restrict__ out) {
    const int o  = blockIdx.x * 256 + threadIdx.x;
    const int b0 = blockIdx.y * 4;

    const u64* __restrict__ x0 = xp + (size_t)(b0 + 0) * 64;
    const u64* __restrict__ x1 = xp + (size_t)(b0 + 1) * 64;
    const u64* __restrict__ x2 = xp + (size_t)(b0 + 2) * 64;
    const u64* __restrict__ x3 = xp + (size_t)(b0 + 3) * 64;

    int a0 = 0, a1 = 0, a2 = 0, a3 = 0;
#pragma unroll 16
    for (int w = 0; w < 64; ++w) {
        const u64 mw = mp[(size_t)w * DIM_OUT + o];
        a0 += __popcll(x0[w] ^ mw);
        a1 += __popcll(x1[w] ^ mw);
        a2 += __popcll(x2[w] ^ mw);
        a3 += __popcll(x3[w] ^ mw);
    }

    const int t = thr[o];
    out[(size_t)(b0 + 0) * DIM_OUT + o] = (DIM_IN - a0) > t ? 1 : 0;
    out[(size_t)(b0 + 1) * DIM_OUT + o] = (DIM_IN - a1) > t ? 1 : 0;
    out[(size_t)(b0 + 2) * DIM_OUT + o] = (DIM_IN - a2) > t ? 1 : 0;
    out[(size_t)(b0 + 3) * DIM_OUT + o] = (DIM_IN - a3) > t ? 1 : 0;
}

// ---------------------------------------------------------------------------
extern "C" void kernel_launch(void* const* d_in, const int* in_sizes, int n_in,
                              void* d_out, int out_size, void* d_ws, size_t ws_size,
                              hipStream_t stream) {
    const void* x     = d_in[0];                 // bool [64][4096]
    const void* masks = d_in[1];                 // bool [4096][4096]
    const int*  thr   = (const int*)d_in[2];     // int32 [4096]
    int* out = (int*)d_out;                      // [64][4096] int32 0/1

    u64* mp = (u64*)d_ws;                                        // 2 MiB
    u64* xp = (u64*)((char*)d_ws + (size_t)64 * DIM_OUT * 8);    // 32 KiB

    pack_kernel<<<dim3(528), dim3(256), 0, stream>>>(masks, x, mp, xp);
    bnn_kernel<<<dim3(16, 16), dim3(256), 0, stream>>>(mp, xp, thr, out);
}

// Round 6
// 42.088 us; speedup vs baseline: 1.1391x; 1.1391x over previous
//
#include <hip/hip_runtime.h>
#include <stdint.h>

#define DIM_IN  4096
#define DIM_OUT 4096
#define BATCH   64
// words along dim_in: 4096/64 = 64

typedef unsigned long long u64;
typedef uint32_t u32;

// NT_SPLIT: row-groups w < NT_SPLIT use normal (L2-allocating) loads and stay
// resident across graph replays (~31 MB < 32 MB aggregate L2); w >= NT_SPLIT
// uses non-temporal loads so the streaming half doesn't thrash the retained
// half. Round 3/4/5 all showed FETCH ~= half of the 67 MB word-encoded masks.
#define NT_SPLIT 30

// ---------------------------------------------------------------------------
// Input-format detection (first 8 u32 words):
//   int32 0/1 or float 0.0/1.0 -> "word" layout (4B per bool)
//   uint8 0/1                  -> "byte" layout (1B per bool)
// Rounds 3-5: FETCH ~33.4 MB (> byte-ideal 16.7 MB, = half of 67 MB) pins the
// encoding as words. Byte path kept for robustness (misclassify P ~ 2^-192).
// ---------------------------------------------------------------------------
__device__ __forceinline__ bool is_word_fmt(const u32* __restrict__ p) {
    bool words = true;
#pragma unroll
    for (int i = 0; i < 8; ++i) {
        u32 v = p[i];
        if (v > 1u && v != 0x3F800000u) words = false;
    }
    return words;
}

// ---------------------------------------------------------------------------
// K1 (fused pack), 1040 blocks x 256 threads (round-4 structure + hybrid NT):
//  blocks 0..1023  : mask pack. One wave per (w, 64-col tile); lane = column.
//                    Lane builds u64 of rows w*64..w*64+63 via 4 batches of
//                    16 independent u32 loads (coalesced 256B/row per wave).
//  blocks 1024..1039: x pack via wave ballot (64 waves x 64 words).
// ---------------------------------------------------------------------------
__global__ __launch_bounds__(256) void pack_kernel(
        const void* __restrict__ masks, const void* __restrict__ x,
        u64* __restrict__ mp, u64* __restrict__ xp) {
    const int bid = blockIdx.x;
    if (bid < 1024) {
        const bool words = is_word_fmt((const u32*)masks);
        const int wid = bid * 4 + (threadIdx.x >> 6);           // 0..4095
        const int w   = wid >> 6;                               // 0..63
        const int o   = ((wid & 63) << 6) + (threadIdx.x & 63); // 0..4095
        const int row0 = w * 64;

        u64 bits = 0;
        if (words) {
            const u32* pw = (const u32*)masks + (size_t)row0 * DIM_OUT + o;
            if (w < NT_SPLIT) {
#pragma unroll
                for (int rb = 0; rb < 4; ++rb) {
                    u32 v[16];
#pragma unroll
                    for (int r = 0; r < 16; ++r)
                        v[r] = pw[(size_t)(rb * 16 + r) * DIM_OUT];
#pragma unroll
                    for (int r = 0; r < 16; ++r)
                        bits |= (u64)(v[r] != 0u) << (rb * 16 + r);
                }
            } else {
#pragma unroll
                for (int rb = 0; rb < 4; ++rb) {
                    u32 v[16];
#pragma unroll
                    for (int r = 0; r < 16; ++r)
                        v[r] = __builtin_nontemporal_load(
                                   pw + (size_t)(rb * 16 + r) * DIM_OUT);
#pragma unroll
                    for (int r = 0; r < 16; ++r)
                        bits |= (u64)(v[r] != 0u) << (rb * 16 + r);
                }
            }
        } else {
            const uint8_t* pb = (const uint8_t*)masks + (size_t)row0 * DIM_OUT + o;
#pragma unroll
            for (int rb = 0; rb < 4; ++rb) {
                uint8_t v[16];
#pragma unroll
                for (int r = 0; r < 16; ++r)
                    v[r] = pb[(size_t)(rb * 16 + r) * DIM_OUT];
#pragma unroll
                for (int r = 0; r < 16; ++r)
                    bits |= (u64)(v[r] != 0u) << (rb * 16 + r);
            }
        }
        mp[(size_t)w * DIM_OUT + o] = bits;
    } else {
        // ------------------- x pack -------------------
        const bool words = is_word_fmt((const u32*)x);
        const int bxid = bid - 1024;                          // 0..15
        const int wave = bxid * 4 + (threadIdx.x >> 6);       // 0..63
        const int lane = threadIdx.x & 63;
        const int base = wave * 64;                           // word index base

#pragma unroll 16
        for (int k = 0; k < 64; ++k) {
            const int idx = base + k;                         // 0..4095
            const size_t e = (size_t)idx * 64 + lane;         // element index
            bool pred;
            if (words) pred = ((const u32*)x)[e] != 0u;
            else       pred = ((const uint8_t*)x)[e] != 0u;
            const u64 m = __ballot(pred);
            if (lane == 0) xp[idx] = m;
        }
    }
}

// ---------------------------------------------------------------------------
// K2: out[b][o] = ((4096 - sum_w popc(xp[b][w] ^ mp[w][o])) > thr[o]) ? 1 : 0
// Output dtype INT32 (bool output -> int32 harness path).
// Grid: (16 o-blocks, 16 b-blocks) x 256 threads; 4 batch rows per thread.
// ---------------------------------------------------------------------------
__global__ __launch_bounds__(256) void bnn_kernel(
        const u64* __restrict__ mp, const u64* __restrict__ xp,
        const int* __restrict__ thr, int* __restrict__ out) {
    const int o  = blockIdx.x * 256 + threadIdx.x;
    const int b0 = blockIdx.y * 4;

    const u64* __restrict__ x0 = xp + (size_t)(b0 + 0) * 64;
    const u64* __restrict__ x1 = xp + (size_t)(b0 + 1) * 64;
    const u64* __restrict__ x2 = xp + (size_t)(b0 + 2) * 64;
    const u64* __restrict__ x3 = xp + (size_t)(b0 + 3) * 64;

    int a0 = 0, a1 = 0, a2 = 0, a3 = 0;
#pragma unroll 16
    for (int w = 0; w < 64; ++w) {
        const u64 mw = mp[(size_t)w * DIM_OUT + o];
        a0 += __popcll(x0[w] ^ mw);
        a1 += __popcll(x1[w] ^ mw);
        a2 += __popcll(x2[w] ^ mw);
        a3 += __popcll(x3[w] ^ mw);
    }

    const int t = thr[o];
    out[(size_t)(b0 + 0) * DIM_OUT + o] = (DIM_IN - a0) > t ? 1 : 0;
    out[(size_t)(b0 + 1) * DIM_OUT + o] = (DIM_IN - a1) > t ? 1 : 0;
    out[(size_t)(b0 + 2) * DIM_OUT + o] = (DIM_IN - a2) > t ? 1 : 0;
    out[(size_t)(b0 + 3) * DIM_OUT + o] = (DIM_IN - a3) > t ? 1 : 0;
}

// ---------------------------------------------------------------------------
extern "C" void kernel_launch(void* const* d_in, const int* in_sizes, int n_in,
                              void* d_out, int out_size, void* d_ws, size_t ws_size,
                              hipStream_t stream) {
    const void* x     = d_in[0];                 // bool [64][4096]
    const void* masks = d_in[1];                 // bool [4096][4096]
    const int*  thr   = (const int*)d_in[2];     // int32 [4096]
    int* out = (int*)d_out;                      // [64][4096] int32 0/1

    u64* mp = (u64*)d_ws;                                        // 2 MiB
    u64* xp = (u64*)((char*)d_ws + (size_t)64 * DIM_OUT * 8);    // 32 KiB

    pack_kernel<<<dim3(1040), dim3(256), 0, stream>>>(masks, x, mp, xp);
    bnn_kernel<<<dim3(16, 16), dim3(256), 0, stream>>>(mp, xp, thr, out);
}